// Round 2
// baseline (494.675 us; speedup 1.0000x reference)
//
#include <hip/hip_runtime.h>
#include <hip/hip_bf16.h>

// Problem constants (from reference setup_inputs)
constexpr int B_DIM   = 64;
constexpr int S_DIM   = 2048;
constexpr int D_DIM   = 512;      // 128 float4 per row
constexpr int NMASK   = 1536;
constexpr int NUNMASK = 512;
constexpr float ALPHA = 0.1f;

constexpr int N_MASK_TOT   = B_DIM * NMASK;     // 98304
constexpr int N_UNMASK_TOT = B_DIM * NUNMASK;   // 32768
constexpr int N_IDX_TOT    = N_MASK_TOT + N_UNMASK_TOT;  // 131072
constexpr int ROWS_TOTAL   = B_DIM * S_DIM;     // 131072

constexpr int BLOCK = 256;   // 2 rows per block iteration (128 threads/row)
constexpr int GRID  = 2048;  // 32 row-iters per block; 8 blocks/CU

// Pass 1: scatter per-row weights into w[b*S + s] (512 KB, L2-resident).
__global__ __launch_bounds__(256) void build_weights_kernel(
    const int* __restrict__ mask_id,
    const int* __restrict__ unmask_id,
    float*     __restrict__ w)
{
    const int tid = blockIdx.x * 256 + threadIdx.x;
    if (tid >= N_IDX_TOT) return;

    const float wm = 1.0f / (float)((long long)B_DIM * NMASK   * D_DIM);
    const float wu = ALPHA / (float)((long long)B_DIM * NUNMASK * D_DIM);

    if (tid < N_MASK_TOT) {
        const int b   = tid / NMASK;
        const int idx = mask_id[tid];
        atomicAdd(w + b * S_DIM + idx, wm);
    } else {
        const int u   = tid - N_MASK_TOT;
        const int b   = u / NUNMASK;
        const int idx = unmask_id[u];
        atomicAdd(w + b * S_DIM + idx, wu);
    }
}

// Pass 2: linear sweep of all rows; skip w==0 rows (wave-uniform branch).
__global__ __launch_bounds__(BLOCK) void weighted_sse_kernel(
    const float* __restrict__ outputs,
    const float* __restrict__ orig,
    const float* __restrict__ wrow,
    float*       __restrict__ out)
{
    const int lane_in_row  = threadIdx.x & 127;  // which float4 of the row
    const int row_in_block = threadIdx.x >> 7;   // 0 or 1

    float acc = 0.0f;

    for (int r = blockIdx.x * 2 + row_in_block; r < ROWS_TOTAL; r += GRID * 2) {
        const float w = wrow[r];                 // broadcast across 128 threads
        if (w != 0.0f) {
            const size_t row_off = (size_t)r * D_DIM;
            const float4 o = ((const float4*)(outputs + row_off))[lane_in_row];
            const float4 t = ((const float4*)(orig    + row_off))[lane_in_row];
            const float dx = o.x - t.x;
            const float dy = o.y - t.y;
            const float dz = o.z - t.z;
            const float dw = o.w - t.w;
            acc += w * (dx * dx + dy * dy + dz * dz + dw * dw);
        }
    }

    // wave (64-lane) shuffle reduction
    #pragma unroll
    for (int off = 32; off > 0; off >>= 1)
        acc += __shfl_down(acc, off, 64);

    __shared__ float sdata[BLOCK / 64];
    const int wid = threadIdx.x >> 6;
    if ((threadIdx.x & 63) == 0) sdata[wid] = acc;
    __syncthreads();

    if (threadIdx.x == 0) {
        float s = 0.0f;
        #pragma unroll
        for (int i = 0; i < BLOCK / 64; ++i) s += sdata[i];
        atomicAdd(out, s);
    }
}

extern "C" void kernel_launch(void* const* d_in, const int* in_sizes, int n_in,
                              void* d_out, int out_size, void* d_ws, size_t ws_size,
                              hipStream_t stream) {
    const float* outputs   = (const float*)d_in[0];
    const float* orig      = (const float*)d_in[1];
    const int*   mask_id   = (const int*)d_in[2];
    const int*   unmask_id = (const int*)d_in[3];
    float* out  = (float*)d_out;
    float* wrow = (float*)d_ws;   // 64*2048 floats = 512 KB

    // d_out / d_ws are re-poisoned to 0xAA before every timed launch.
    hipMemsetAsync(out,  0, sizeof(float), stream);
    hipMemsetAsync(wrow, 0, (size_t)ROWS_TOTAL * sizeof(float), stream);

    build_weights_kernel<<<(N_IDX_TOT + 255) / 256, 256, 0, stream>>>(
        mask_id, unmask_id, wrow);

    weighted_sse_kernel<<<GRID, BLOCK, 0, stream>>>(outputs, orig, wrow, out);
}